// Round 12
// baseline (18.335 us; speedup 1.0000x reference)
//
#include <hip/hip_runtime.h>

#define BS 1024
#define D_IN 512
#define D_OUT 512
#define N_MASKS 8

typedef short bf16x8 __attribute__((ext_vector_type(8)));
typedef float f32x4 __attribute__((ext_vector_type(4)));

// ws (int units): wsi[0..8] group offsets; wsi[16+p] row perm, p in [0,1024)

__device__ __forceinline__ ushort f2bf(float f) {
    union { float f; unsigned u; } x; x.f = f;
    unsigned r = (x.u + 0x7fffu + ((x.u >> 16) & 1u)) >> 16;  // RNE
    return (ushort)r;
}

__device__ __forceinline__ bf16x8 pack8(float4 a0, float4 a1) {
    union { uint u[4]; bf16x8 v; } r;
    r.u[0] = (uint)f2bf(a0.x) | ((uint)f2bf(a0.y) << 16);
    r.u[1] = (uint)f2bf(a0.z) | ((uint)f2bf(a0.w) << 16);
    r.u[2] = (uint)f2bf(a1.x) | ((uint)f2bf(a1.y) << 16);
    r.u[3] = (uint)f2bf(a1.z) | ((uint)f2bf(a1.w) << 16);
    return r.v;
}

// ---------------- Kernel A: counting sort of rows by state ----------------
__global__ void __launch_bounds__(BS) sort_kernel(const int* __restrict__ state,
                                                  int* __restrict__ wsi) {
    __shared__ int cnt[N_MASKS];
    __shared__ int offs[N_MASKS + 1];
    const int tid = threadIdx.x;
    if (tid < N_MASKS) cnt[tid] = 0;
    __syncthreads();
    const int s = state[tid];
    atomicAdd(&cnt[s], 1);
    __syncthreads();
    if (tid == 0) {
        int acc = 0;
        for (int i = 0; i < N_MASKS; ++i) { offs[i] = acc; acc += cnt[i]; }
        offs[N_MASKS] = acc;
    }
    __syncthreads();
    if (tid <= N_MASKS) wsi[tid] = offs[tid];
    if (tid < N_MASKS) cnt[tid] = offs[tid];   // scatter cursors
    __syncthreads();
    const int pos = atomicAdd(&cnt[s], 1);
    wsi[16 + pos] = tid;
}

// ---------------- Fused: stage kern*mask slice -> LDS fragments -> MFMA ----------------
// grid = (mask n fastest -> XCD n, 16 col-tiles of 32, 2 row-halves). 512 thr = 8 waves.
// No written global intermediate: kern/masks/x are read-only L3-warm inputs.
// LDS wlds layout (r2-verified fragment-linear, 2 col-fragments cb=0/1):
//   slot(kb,cb,lane=(g,cl)) = (kb*2+cb)*64 + g*16 + cl, 8 ushorts each:
//   B[k = kb*32 + g*8 + j][col = c0g + cb*16 + cl], j = 0..7.
__global__ void __launch_bounds__(512, 4) fused_kernel(
    const float* __restrict__ x, const float* __restrict__ kern,
    const float* __restrict__ masks, const int* __restrict__ wsi,
    float* __restrict__ out)
{
    __shared__ ushort wlds[16 * 2 * 64 * 8];   // 32 KB
    __shared__ float red[4][2][64][4];          // 8 KB: kh=1 partials per rowtile slot

    const int n   = blockIdx.x;
    const int c0g = blockIdx.y * 32;
    const int rh  = blockIdx.z;
    const int tid = threadIdx.x;
    const float* __restrict__ maskn = masks + (size_t)n * (D_IN * D_OUT);

    // ---- stage: coalesced float4 loads, in-register bf16 pack, LDS fragment write ----
    // chunk = (k-pair p, col4 q): lanes q-fastest -> 128B contiguous row segments.
    #pragma unroll
    for (int it = 0; it < 4; ++it) {
        const int chunk = it * 512 + tid;       // [0, 2048)
        const int q = chunk & 7;
        const int p = chunk >> 3;               // k-pair [0,256)
        const size_t gidx = (size_t)(2 * p) * D_OUT + c0g + q * 4;
        const float4 k0 = *(const float4*)&kern[gidx];
        const float4 k1 = *(const float4*)&kern[gidx + D_OUT];
        const float4 m0 = *(const float4*)&maskn[gidx];
        const float4 m1 = *(const float4*)&maskn[gidx + D_OUT];
        // k = 2p: kb = p>>4, g = (p>>2)&3, pair index h = p&3
        const int kb = p >> 4, gg = (p >> 2) & 3, h = p & 3;
        const float w0[4] = {k0.x*m0.x, k0.y*m0.y, k0.z*m0.z, k0.w*m0.w};
        const float w1[4] = {k1.x*m1.x, k1.y*m1.y, k1.z*m1.z, k1.w*m1.w};
        #pragma unroll
        for (int j = 0; j < 4; ++j) {
            const int c = q * 4 + j;            // local col 0..31
            const int slot = (kb * 2 + (c >> 4)) * 64 + gg * 16 + (c & 15);
            ((uint*)wlds)[slot * 4 + h] =
                (uint)f2bf(w0[j]) | ((uint)f2bf(w1[j]) << 16);
        }
    }

    const int off0 = wsi[n], off1 = wsi[n + 1];
    const int gcnt = off1 - off0;
    const int T  = (gcnt + 15) >> 4;                       // rowtiles in group
    const int Tb = (T > rh) ? ((T - rh + 1) >> 1) : 0;     // tiles for this block
    const int M  = (Tb + 3) >> 2;                          // uniform wave trips

    const int lane = tid & 63;
    const int wid  = tid >> 6;
    const int rtl  = wid >> 1;      // rowtile slot 0..3
    const int kh   = wid & 1;       // K-half
    const int g    = lane >> 4;
    const int cl   = lane & 15;

    __syncthreads();

    for (int m = 0; m < M; ++m) {
        const int rt = rh + 2 * (rtl + 4 * m);   // this wave's rowtile
        const bool active = (rt < T);
        f32x4 acc0 = {0.f,0.f,0.f,0.f}, acc1 = {0.f,0.f,0.f,0.f};
        int rv = -1;
        if (active) {
            const int p = off0 + rt * 16 + cl;
            rv = (p < off1) ? wsi[16 + p] : -1;
            const float* xr = x + (size_t)(rv < 0 ? 0 : rv) * D_IN + kh * 256 + g * 8;
            #pragma unroll
            for (int i = 0; i < 8; ++i) {        // kb global = kh*8 + i
                const float4 a0 = *(const float4*)(xr + i * 32);
                const float4 a1 = *(const float4*)(xr + i * 32 + 4);
                const bf16x8 a = pack8(a0, a1);
                const int kbg = kh * 8 + i;
                const bf16x8 b0 = *(const bf16x8*)&wlds[((kbg * 2 + 0) * 64 + lane) * 8];
                const bf16x8 b1 = *(const bf16x8*)&wlds[((kbg * 2 + 1) * 64 + lane) * 8];
                acc0 = __builtin_amdgcn_mfma_f32_16x16x32_bf16(a, b0, acc0, 0, 0, 0);
                acc1 = __builtin_amdgcn_mfma_f32_16x16x32_bf16(a, b1, acc1, 0, 0, 0);
            }
        }
        if (kh) {
            *(f32x4*)&red[rtl][0][lane][0] = acc0;
            *(f32x4*)&red[rtl][1][lane][0] = acc1;
        }
        __syncthreads();
        if (!kh && active) {
            acc0 += *(const f32x4*)&red[rtl][0][lane][0];
            acc1 += *(const f32x4*)&red[rtl][1][lane][0];
            // C/D: col = cl, row-in-tile = g*4 + r
            #pragma unroll
            for (int r = 0; r < 4; ++r) {
                const int brow = __shfl(rv, g * 4 + r);
                if (brow >= 0) {
                    float* op = out + (size_t)brow * D_OUT + c0g;
                    op[cl]      = fmaxf(acc0[r], 0.f);
                    op[16 + cl] = fmaxf(acc1[r], 0.f);
                }
            }
        }
        __syncthreads();   // protect red before next trip
    }
}

extern "C" void kernel_launch(void* const* d_in, const int* in_sizes, int n_in,
                              void* d_out, int out_size, void* d_ws, size_t ws_size,
                              hipStream_t stream) {
    const float* x     = (const float*)d_in[0];
    const int*   state = (const int*)d_in[1];
    const float* kern  = (const float*)d_in[2];
    const float* masks = (const float*)d_in[3];
    float* out = (float*)d_out;
    int*   wsi = (int*)d_ws;

    sort_kernel<<<1, BS, 0, stream>>>(state, wsi);
    dim3 grid(N_MASKS, 16, 2);
    fused_kernel<<<grid, 512, 0, stream>>>(x, kern, masks, wsi, out);
}